// Round 11
// baseline (2738.092 us; speedup 1.0000x reference)
//
#include <hip/hip_runtime.h>

#define NODES 100000
#define NEDGE 1600000
#define SCHUNK 1024
#define SBLOCKS ((NODES + SCHUNK - 1) / SCHUNK)  // 98
#define NPART 8
#define PSIZE (NODES / NPART)  // 12500
#define BCAP 204800            // bucket capacity (mean 200K, >11 sigma headroom)
#define CSRCHUNK 2048

typedef _Float16 half8 __attribute__((ext_vector_type(8)));
typedef float floatx4 __attribute__((ext_vector_type(4)));
typedef float floatx2 __attribute__((ext_vector_type(2)));

// ------------------------------------------------------------ fp16 helpers

static __device__ __forceinline__ unsigned int packh2(float a, float b) {
    union { _Float16 h; unsigned short s; } x, y;
    x.h = (_Float16)a; y.h = (_Float16)b;
    return (unsigned int)x.s | ((unsigned int)y.s << 16);
}
static __device__ __forceinline__ float2 unpackh2(unsigned int u) {
    union { unsigned short s; _Float16 h; } x, y;
    x.s = (unsigned short)(u & 0xffffu);
    y.s = (unsigned short)(u >> 16);
    return make_float2((float)x.h, (float)y.h);
}

// ------------------------------------------------------------ fp8 helpers

static __device__ __forceinline__ unsigned char f2fp8(float x) {
    return (unsigned char)(__builtin_amdgcn_cvt_pk_fp8_f32(x, x, 0, false) & 0xff);
}
template <bool HI>
static __device__ __forceinline__ float2 fp8x2_to_f32(unsigned int u) {
    floatx2 r = __builtin_amdgcn_cvt_pk_f32_fp8(u, HI);
    return make_float2(r.x, r.y);
}

// ------------------------------------------------------------ XCD id
// Physical accelerator-die id of the CU this wave runs on (0..7 on MI355X).

static __device__ __forceinline__ int xcd_id() {
    unsigned x;
    asm volatile("s_getreg_b32 %0, hwreg(HW_REG_XCC_ID)" : "=s"(x));
    return (int)(x & 7u);
}

// ------------------------------------------- weight convert (fp32 -> fp16^T)

static __global__ __launch_bounds__(256) void wconv_kernel(
    const float* __restrict__ W1l, const float* __restrict__ W1r,
    const float* __restrict__ W2l, const float* __restrict__ W2r,
    _Float16* __restrict__ WT1, _Float16* __restrict__ WT2) {
    int idx = blockIdx.x * 256 + threadIdx.x;
    if (idx < 256 * 128) {
        int n = idx >> 7, k = idx & 127;
        float v = (n < 128) ? W1l[k * 128 + n] : W1r[k * 128 + (n - 128)];
        WT1[n * 128 + k] = (_Float16)v;
    } else if (idx < 256 * 128 + 128 * 128) {
        int i2 = idx - 256 * 128;
        int n = i2 >> 7, k = i2 & 127;
        float v = (n < 64) ? W2l[k * 64 + n] : W2r[k * 64 + (n - 64)];
        WT2[n * 128 + k] = (_Float16)v;
    }
}

// ---------------------------------------------------------------- CSR build

// zero deg[na] and meta[nb] in one launch
static __global__ void zero2_kernel(int* __restrict__ a, int na,
                                    int* __restrict__ b, int nb) {
    int i = blockIdx.x * blockDim.x + threadIdx.x;
    int stride = gridDim.x * blockDim.x;
    for (; i < na + nb; i += stride) {
        if (i < na) a[i] = 0;
        else        b[i - na] = 0;
    }
}

// P1: stream edges once, pack (src | dst_local<<17) into 8 dst-range
// buckets.  Per-wave ballot aggregation -> one atomicAdd per wave per
// bucket; allocations are sequential per bucket -> near-1x write amp.
static __global__ __launch_bounds__(256) void bucket_kernel(
    const int* __restrict__ src, const int* __restrict__ dst,
    int* __restrict__ meta /* [0..7] bucket counts */,
    unsigned int* __restrict__ buckets) {
    int i = blockIdx.x * 256 + threadIdx.x;
    int stride = gridDim.x * 256;
    int lane = threadIdx.x & 63;
    for (int e = i; ; e += stride) {
        bool valid = (e < NEDGE);
        unsigned long long vm = __ballot(valid);
        if (!vm) break;
        int b = -1;
        unsigned pk = 0u;
        if (valid) {
            int d = dst[e];
            int sv = src[e];
            b = d / PSIZE;                               // 0..7
            pk = (unsigned)sv | ((unsigned)(d - b * PSIZE) << 17);
        }
#pragma unroll
        for (int bk = 0; bk < 8; ++bk) {
            unsigned long long m = __ballot(valid && b == bk);
            if (!m) continue;
            int leader = __ffsll(m) - 1;
            int cnt = __popcll(m);
            int base = 0;
            if (lane == leader) base = atomicAdd(&meta[bk], cnt);
            base = __shfl(base, leader);
            if (valid && b == bk) {
                int pos = base + __popcll(m & ((1ull << lane) - 1));
                if (pos < BCAP) buckets[(size_t)bk * BCAP + pos] = pk;
            }
        }
    }
}

// Pinned degree count: each block processes the bucket of the XCD it is
// physically running on (chunk work-stealing) -> all reads/atomics stay in
// the local L2; no dispatch-mapping assumption.
static __global__ __launch_bounds__(256) void count_bucket_kernel(
    const unsigned int* __restrict__ buckets, const int* __restrict__ meta,
    int* __restrict__ ticket /* meta+8 */, int* __restrict__ deg) {
    const int xcc = xcd_id();
    const unsigned int* bk = buckets + (size_t)xcc * BCAP;
    const int n = min(meta[xcc], BCAP);
    const int lo = xcc * PSIZE;
    __shared__ int sT;
    for (;;) {
        if (threadIdx.x == 0) sT = atomicAdd(&ticket[xcc], 1);
        __syncthreads();
        int start = sT * CSRCHUNK;
        __syncthreads();
        if (start >= n) break;
        int end = min(start + CSRCHUNK, n);
        for (int i = start + threadIdx.x; i < end; i += 256)
            atomicAdd(&deg[lo + (int)(bk[i] >> 17)], 1);
    }
}

static __global__ __launch_bounds__(256) void scan_partial_kernel(
    const int* __restrict__ deg, int* __restrict__ partials) {
    __shared__ int ss[256];
    int t = threadIdx.x;
    int base = blockIdx.x * SCHUNK + t * 4;
    int s = 0;
#pragma unroll
    for (int j = 0; j < 4; ++j) {
        int i = base + j;
        if (i < NODES) s += deg[i];
    }
    ss[t] = s;
    __syncthreads();
    for (int off = 128; off > 0; off >>= 1) {
        if (t < off) ss[t] += ss[t + off];
        __syncthreads();
    }
    if (t == 0) partials[blockIdx.x] = ss[0];
}

static __global__ __launch_bounds__(128) void scan_offsets_kernel(
    const int* __restrict__ partials, int* __restrict__ block_off,
    int* __restrict__ row_ptr) {
    __shared__ int ss[128];
    int t = threadIdx.x;
    int v = (t < SBLOCKS) ? partials[t] : 0;
    ss[t] = v;
    __syncthreads();
    for (int off = 1; off < 128; off <<= 1) {
        int u = (t >= off) ? ss[t - off] : 0;
        __syncthreads();
        ss[t] += u;
        __syncthreads();
    }
    if (t < SBLOCKS) block_off[t] = ss[t] - v;  // exclusive
    if (t == 127) row_ptr[NODES] = ss[127];
}

static __global__ __launch_bounds__(256) void scan_scatter_kernel(
    const int* deg, const int* __restrict__ block_off,
    int* __restrict__ row_ptr, int* cursor) {
    __shared__ int ss[256];
    int t = threadIdx.x;
    int base = blockIdx.x * SCHUNK + t * 4;
    int d[4];
    int s = 0;
#pragma unroll
    for (int j = 0; j < 4; ++j) {
        int i = base + j;
        d[j] = (i < NODES) ? deg[i] : 0;
        s += d[j];
    }
    ss[t] = s;
    __syncthreads();
    for (int off = 1; off < 256; off <<= 1) {
        int u = (t >= off) ? ss[t - off] : 0;
        __syncthreads();
        ss[t] += u;
        __syncthreads();
    }
    int run = block_off[blockIdx.x] + ss[t] - s;
#pragma unroll
    for (int j = 0; j < 4; ++j) {
        int i = base + j;
        if (i < NODES) {
            row_ptr[i] = run;
            cursor[i] = run;
            run += d[j];
        }
    }
}

// Pinned CSR fill: same work-stealing structure; per-XCD working set =
// bucket (0.84 MB, likely still L2-hot from count) + col slice (0.8 MB)
// + cursor slice -> col lines fill completely before writeback.
static __global__ __launch_bounds__(256) void fill_bucket_kernel(
    const unsigned int* __restrict__ buckets, const int* __restrict__ meta,
    int* __restrict__ ticket /* meta+16 */, int* __restrict__ cursor,
    int* __restrict__ col) {
    const int xcc = xcd_id();
    const unsigned int* bk = buckets + (size_t)xcc * BCAP;
    const int n = min(meta[xcc], BCAP);
    const int lo = xcc * PSIZE;
    __shared__ int sT;
    for (;;) {
        if (threadIdx.x == 0) sT = atomicAdd(&ticket[xcc], 1);
        __syncthreads();
        int start = sT * CSRCHUNK;
        __syncthreads();
        if (start >= n) break;
        int end = min(start + CSRCHUNK, n);
        for (int i = start + threadIdx.x; i < end; i += 256) {
            unsigned pk = bk[i];
            int sv = (int)(pk & 0x1FFFFu);
            int d = lo + (int)(pk >> 17);
            int pos = atomicAdd(&cursor[d], 1);
            col[pos] = sv;
        }
    }
}

// -------------------------------------------------- layer-1 MFMA dual GEMM
// U8 = fp8(X @ W1l)  (waves 0-1),  V16 = fp16(X @ W1r + b1)  (waves 2-3).

static __global__ __launch_bounds__(256) void gemm1_mfma_kernel(
    const float* __restrict__ X, const _Float16* __restrict__ WT1,
    const float* __restrict__ b1,
    unsigned char* __restrict__ U8, _Float16* __restrict__ V16) {
    __shared__ _Float16 sX[64][136];
    const int tid = threadIdx.x;
    const int row0 = blockIdx.x * 64;
    {
        int c4 = (tid & 31) * 4;
        int r0 = tid >> 5;
#pragma unroll
        for (int p = 0; p < 8; ++p) {
            int r = r0 + p * 8;
            int row = row0 + r;
            float4 v = make_float4(0.f, 0.f, 0.f, 0.f);
            if (row < NODES) v = *(const float4*)(X + (size_t)row * 128 + c4);
            sX[r][c4 + 0] = (_Float16)v.x;
            sX[r][c4 + 1] = (_Float16)v.y;
            sX[r][c4 + 2] = (_Float16)v.z;
            sX[r][c4 + 3] = (_Float16)v.w;
        }
    }
    __syncthreads();

    const int wave = tid >> 6;
    const int lane = tid & 63;
    const int l15 = lane & 15;
    const int quad = lane >> 4;

    floatx4 acc[4][4];  // [j][m]
#pragma unroll
    for (int j = 0; j < 4; ++j)
#pragma unroll
        for (int m = 0; m < 4; ++m) acc[j][m] = (floatx4){0.f, 0.f, 0.f, 0.f};

    const _Float16* Wbase = WT1 + (size_t)(wave * 64 + l15) * 128 + quad * 8;

    for (int k0 = 0; k0 < 128; k0 += 32) {
        half8 a[4];
#pragma unroll
        for (int m = 0; m < 4; ++m)
            a[m] = *(const half8*)&sX[m * 16 + l15][quad * 8 + k0];
#pragma unroll
        for (int j = 0; j < 4; ++j) {
            half8 b = *(const half8*)(Wbase + (size_t)j * 16 * 128 + k0);
#pragma unroll
            for (int m = 0; m < 4; ++m)
                acc[j][m] = __builtin_amdgcn_mfma_f32_16x16x32_f16(a[m], b, acc[j][m], 0, 0, 0);
        }
    }

    const int nbase = wave * 64 + l15;
    if (wave < 2) {
#pragma unroll
        for (int j = 0; j < 4; ++j) {
            int n = nbase + j * 16;
#pragma unroll
            for (int m = 0; m < 4; ++m)
#pragma unroll
                for (int r = 0; r < 4; ++r) {
                    int row = row0 + m * 16 + quad * 4 + r;
                    if (row < NODES)
                        U8[(size_t)row * 128 + n] = f2fp8(acc[j][m][r]);
                }
        }
    } else {
#pragma unroll
        for (int j = 0; j < 4; ++j) {
            int nn = nbase + j * 16 - 128;
            float badd = b1[nn];
#pragma unroll
            for (int m = 0; m < 4; ++m)
#pragma unroll
                for (int r = 0; r < 4; ++r) {
                    int row = row0 + m * 16 + quad * 4 + r;
                    if (row < NODES)
                        V16[(size_t)row * 128 + nn] = (_Float16)(acc[j][m][r] + badd);
                }
        }
    }
}

// -------------------------------------------------- layer-1 aggregate
// One wave per node; 4 groups of 16 lanes split the edge stream
// -> 16 outstanding gathers/wave, zero divergence.

static __global__ __launch_bounds__(256) void agg1_kernel(
    const unsigned char* __restrict__ U8, const int* __restrict__ row_ptr,
    const int* __restrict__ col, unsigned int* __restrict__ H32) {
    int node = (int)((blockIdx.x * 256 + threadIdx.x) >> 6);
    int lane = threadIdx.x & 63;
    if (node >= NODES) return;
    const int g = lane >> 4;
    const int l16 = lane & 15;
    int s = row_ptr[node];
    int e = row_ptr[node + 1];
    float inv = 1.0f / (float)max(e - s, 1);

    float acc[8];
#pragma unroll
    for (int i = 0; i < 8; ++i) acc[i] = 0.f;

    int p = s + g;
    for (; p + 12 < e; p += 16) {
        int c0 = col[p], c1 = col[p + 4], c2 = col[p + 8], c3 = col[p + 12];
        uint2 u0 = *(const uint2*)(U8 + (size_t)c0 * 128 + l16 * 8);
        uint2 u1 = *(const uint2*)(U8 + (size_t)c1 * 128 + l16 * 8);
        uint2 u2 = *(const uint2*)(U8 + (size_t)c2 * 128 + l16 * 8);
        uint2 u3 = *(const uint2*)(U8 + (size_t)c3 * 128 + l16 * 8);
#pragma unroll
        for (int q = 0; q < 4; ++q) {
            uint2 u = (q == 0) ? u0 : (q == 1) ? u1 : (q == 2) ? u2 : u3;
            float2 a0 = fp8x2_to_f32<false>(u.x), a1 = fp8x2_to_f32<true>(u.x);
            float2 a2 = fp8x2_to_f32<false>(u.y), a3 = fp8x2_to_f32<true>(u.y);
            acc[0] += a0.x; acc[1] += a0.y; acc[2] += a1.x; acc[3] += a1.y;
            acc[4] += a2.x; acc[5] += a2.y; acc[6] += a3.x; acc[7] += a3.y;
        }
    }
    for (; p < e; p += 4) {
        uint2 u = *(const uint2*)(U8 + (size_t)col[p] * 128 + l16 * 8);
        float2 a0 = fp8x2_to_f32<false>(u.x), a1 = fp8x2_to_f32<true>(u.x);
        float2 a2 = fp8x2_to_f32<false>(u.y), a3 = fp8x2_to_f32<true>(u.y);
        acc[0] += a0.x; acc[1] += a0.y; acc[2] += a1.x; acc[3] += a1.y;
        acc[4] += a2.x; acc[5] += a2.y; acc[6] += a3.x; acc[7] += a3.y;
    }

#pragma unroll
    for (int i = 0; i < 8; ++i) {
        acc[i] += __shfl_xor(acc[i], 16);
        acc[i] += __shfl_xor(acc[i], 32);
    }

    if (lane < 16) {
        uint4 vv = *(const uint4*)(H32 + (size_t)node * 64 + l16 * 4);
        float2 v0 = unpackh2(vv.x), v1 = unpackh2(vv.y);
        float2 v2 = unpackh2(vv.z), v3 = unpackh2(vv.w);
        uint4 o;
        o.x = packh2(fmaxf(acc[0] * inv + v0.x, 0.f), fmaxf(acc[1] * inv + v0.y, 0.f));
        o.y = packh2(fmaxf(acc[2] * inv + v1.x, 0.f), fmaxf(acc[3] * inv + v1.y, 0.f));
        o.z = packh2(fmaxf(acc[4] * inv + v2.x, 0.f), fmaxf(acc[5] * inv + v2.y, 0.f));
        o.w = packh2(fmaxf(acc[6] * inv + v3.x, 0.f), fmaxf(acc[7] * inv + v3.y, 0.f));
        *(uint4*)(H32 + (size_t)node * 64 + l16 * 4) = o;
    }
}

// -------------------------------------------------- layer-2 MFMA dual GEMM

static __global__ __launch_bounds__(256) void gemm2_mfma_kernel(
    const _Float16* __restrict__ H16, const _Float16* __restrict__ WT2,
    const float* __restrict__ b2,
    _Float16* __restrict__ T16, float* __restrict__ OUT) {
    __shared__ _Float16 sX[64][136];
    const int tid = threadIdx.x;
    const int row0 = blockIdx.x * 64;
    {
        int c8 = (tid & 15) * 8;
        int r0 = tid >> 4;
#pragma unroll
        for (int p = 0; p < 4; ++p) {
            int r = r0 + p * 16;
            int row = row0 + r;
            uint4 v = make_uint4(0u, 0u, 0u, 0u);
            if (row < NODES) v = *(const uint4*)(H16 + (size_t)row * 128 + c8);
            *(uint4*)&sX[r][c8] = v;
        }
    }
    __syncthreads();

    const int wave = tid >> 6;
    const int lane = tid & 63;
    const int l15 = lane & 15;
    const int quad = lane >> 4;

    floatx4 acc[2][4];
#pragma unroll
    for (int j = 0; j < 2; ++j)
#pragma unroll
        for (int m = 0; m < 4; ++m) acc[j][m] = (floatx4){0.f, 0.f, 0.f, 0.f};

    const _Float16* Wbase = WT2 + (size_t)(wave * 32 + l15) * 128 + quad * 8;

    for (int k0 = 0; k0 < 128; k0 += 32) {
        half8 a[4];
#pragma unroll
        for (int m = 0; m < 4; ++m)
            a[m] = *(const half8*)&sX[m * 16 + l15][quad * 8 + k0];
#pragma unroll
        for (int j = 0; j < 2; ++j) {
            half8 b = *(const half8*)(Wbase + (size_t)j * 16 * 128 + k0);
#pragma unroll
            for (int m = 0; m < 4; ++m)
                acc[j][m] = __builtin_amdgcn_mfma_f32_16x16x32_f16(a[m], b, acc[j][m], 0, 0, 0);
        }
    }

    const int nbase = wave * 32 + l15;
#pragma unroll
    for (int j = 0; j < 2; ++j) {
        int n = nbase + j * 16;
        bool isOut = (n >= 64);
        int nn = isOut ? n - 64 : n;
        float badd = isOut ? b2[nn] : 0.f;
#pragma unroll
        for (int m = 0; m < 4; ++m)
#pragma unroll
            for (int r = 0; r < 4; ++r) {
                int row = row0 + m * 16 + quad * 4 + r;
                if (row < NODES) {
                    float v = acc[j][m][r] + badd;
                    if (isOut) OUT[(size_t)row * 64 + nn] = v;
                    else       T16[(size_t)row * 64 + nn] = (_Float16)v;
                }
            }
    }
}

// -------------------------------------------------- layer-2 aggregate

static __global__ __launch_bounds__(256) void agg2_kernel(
    const unsigned int* __restrict__ T32, const int* __restrict__ row_ptr,
    const int* __restrict__ col, float* __restrict__ OUT) {
    int node = (int)((blockIdx.x * 256 + threadIdx.x) >> 6);
    int lane = threadIdx.x & 63;
    if (node >= NODES) return;
    const int g = lane >> 4;
    const int l16 = lane & 15;
    int s = row_ptr[node];
    int e = row_ptr[node + 1];
    float inv = 1.0f / (float)max(e - s, 1);

    float acc[4];
#pragma unroll
    for (int i = 0; i < 4; ++i) acc[i] = 0.f;

    int p = s + g;
    for (; p + 12 < e; p += 16) {
        int c0 = col[p], c1 = col[p + 4], c2 = col[p + 8], c3 = col[p + 12];
        uint2 u0 = *(const uint2*)(T32 + (size_t)c0 * 32 + l16 * 2);
        uint2 u1 = *(const uint2*)(T32 + (size_t)c1 * 32 + l16 * 2);
        uint2 u2 = *(const uint2*)(T32 + (size_t)c2 * 32 + l16 * 2);
        uint2 u3 = *(const uint2*)(T32 + (size_t)c3 * 32 + l16 * 2);
#pragma unroll
        for (int q = 0; q < 4; ++q) {
            uint2 u = (q == 0) ? u0 : (q == 1) ? u1 : (q == 2) ? u2 : u3;
            float2 a0 = unpackh2(u.x), a1 = unpackh2(u.y);
            acc[0] += a0.x; acc[1] += a0.y; acc[2] += a1.x; acc[3] += a1.y;
        }
    }
    for (; p < e; p += 4) {
        uint2 u = *(const uint2*)(T32 + (size_t)col[p] * 32 + l16 * 2);
        float2 a0 = unpackh2(u.x), a1 = unpackh2(u.y);
        acc[0] += a0.x; acc[1] += a0.y; acc[2] += a1.x; acc[3] += a1.y;
    }

#pragma unroll
    for (int i = 0; i < 4; ++i) {
        acc[i] += __shfl_xor(acc[i], 16);
        acc[i] += __shfl_xor(acc[i], 32);
    }

    if (lane < 16) {
        float4 o = *(float4*)(OUT + (size_t)node * 64 + l16 * 4);
        o.x += acc[0] * inv;
        o.y += acc[1] * inv;
        o.z += acc[2] * inv;
        o.w += acc[3] * inv;
        *(float4*)(OUT + (size_t)node * 64 + l16 * 4) = o;
    }
}

// ---------------------------------------------------------------- launch

extern "C" void kernel_launch(void* const* d_in, const int* in_sizes, int n_in,
                              void* d_out, int out_size, void* d_ws, size_t ws_size,
                              hipStream_t stream) {
    const float* x   = (const float*)d_in[0];
    const float* W1l = (const float*)d_in[1];
    const float* b1  = (const float*)d_in[2];
    const float* W1r = (const float*)d_in[3];
    const float* W2l = (const float*)d_in[4];
    const float* b2  = (const float*)d_in[5];
    const float* W2r = (const float*)d_in[6];
    const int*   ei  = (const int*)d_in[7];
    const int* esrc = ei;          // edge_index[0]
    const int* edst = ei + NEDGE;  // edge_index[1]
    float* out = (float*)d_out;

    // ws layout — ~45.3 MB (well inside the proven 58.4 MB envelope).
    char* ws = (char*)d_ws;
    size_t off = 0;
    int* row_ptr  = (int*)(ws + off); off += (((size_t)(NODES + 1) * 4) + 255) & ~(size_t)255;
    int* col      = (int*)(ws + off); off += (size_t)NEDGE * 4;
    int* partials = (int*)(ws + off); off += 512;
    int* blockoff = (int*)(ws + off); off += 512;
    int* meta     = (int*)(ws + off); off += 128;   // [0..7] bucket cnt, [8..15] count tickets, [16..23] fill tickets
    _Float16* WT1 = (_Float16*)(ws + off); off += 256 * 128 * 2;
    _Float16* WT2 = (_Float16*)(ws + off); off += 128 * 128 * 2;
    unsigned char* U8 = (unsigned char*)(ws + off); off += (size_t)NODES * 128;
    _Float16* V16 = (_Float16*)(ws + off); off += (size_t)NODES * 128 * 2;
    int* cursor = (int*)U8;                 // deg/cursor alias U8 (dead until gemm1)
    _Float16* T16 = (_Float16*)U8;          // T aliases U8 (dead after agg1)
    unsigned int* buckets = (unsigned int*)V16;  // 8*BCAP*4 = 6.55 MB aliases V16 (dead until gemm1)

    // ---- weight conversion + CSR build (bucketed, XCD-pinned)
    wconv_kernel<<<192, 256, 0, stream>>>(W1l, W1r, W2l, W2r, WT1, WT2);
    zero2_kernel<<<256, 256, 0, stream>>>(cursor, NODES, meta, 32);
    bucket_kernel<<<2048, 256, 0, stream>>>(esrc, edst, meta, buckets);
    count_bucket_kernel<<<2048, 256, 0, stream>>>(buckets, meta, meta + 8, cursor);
    scan_partial_kernel<<<SBLOCKS, 256, 0, stream>>>(cursor, partials);
    scan_offsets_kernel<<<1, 128, 0, stream>>>(partials, blockoff, row_ptr);
    scan_scatter_kernel<<<SBLOCKS, 256, 0, stream>>>(cursor, blockoff, row_ptr, cursor);
    fill_bucket_kernel<<<2048, 256, 0, stream>>>(buckets, meta, meta + 16, cursor, col);

    const int gemm_grid = (NODES + 63) / 64;  // 1563
    const int agg_grid  = (NODES + 3) / 4;    // one wave per node

    // ---- layer 1
    gemm1_mfma_kernel<<<gemm_grid, 256, 0, stream>>>(x, WT1, b1, U8, V16);
    agg1_kernel<<<agg_grid, 256, 0, stream>>>(U8, row_ptr, col, (unsigned int*)V16);

    // ---- layer 2 (H = V16 in place)
    gemm2_mfma_kernel<<<gemm_grid, 256, 0, stream>>>(V16, WT2, b2, T16, out);
    agg2_kernel<<<agg_grid, 256, 0, stream>>>(
        (const unsigned int*)T16, row_ptr, col, out);
}